// Round 1
// baseline (306.797 us; speedup 1.0000x reference)
//
#include <hip/hip_runtime.h>
#include <stdint.h>

#define B_ 4
#define T_ 1024
#define E_ 1024
#define H_ 16
#define HS_ 64
#define BT_ 4096

typedef unsigned short u16;
typedef __attribute__((ext_vector_type(8))) short bf16x8;
typedef __attribute__((ext_vector_type(4))) float f32x4;

__device__ __forceinline__ u16 f2bf(float f) {
    unsigned u = __float_as_uint(f);
    u += 0x7fff + ((u >> 16) & 1);   // round-to-nearest-even
    return (u16)(u >> 16);
}

__device__ __forceinline__ void gll16(const void* g, void* l) {
    __builtin_amdgcn_global_load_lds(
        (const __attribute__((address_space(1))) unsigned int*)g,
        (__attribute__((address_space(3))) unsigned int*)l, 16, 0, 0);
}

// ---------------------------------------------------------------------------
// LayerNorm for all three streams. One block (256 thr) per row of 1024.
// grid.x = 3*4096. which = row/4096 selects v/k/q.
// ---------------------------------------------------------------------------
__global__ __launch_bounds__(256) void ln_all(
    const float* __restrict__ v, const float* __restrict__ k,
    const float* __restrict__ q, const float* __restrict__ g,
    const float* __restrict__ b,
    u16* __restrict__ vn, u16* __restrict__ kn, u16* __restrict__ qn)
{
    int row = blockIdx.x;
    int which = row >> 12;
    int r = row & 4095;
    const float* src = which == 0 ? v : which == 1 ? k : q;
    u16* dst = which == 0 ? vn : which == 1 ? kn : qn;

    int t = threadIdx.x;
    float4 x = ((const float4*)(src + (size_t)r * E_))[t];
    float s  = x.x + x.y + x.z + x.w;
    float ss = x.x * x.x + x.y * x.y + x.z * x.z + x.w * x.w;
    for (int off = 32; off; off >>= 1) {
        s  += __shfl_down(s, off, 64);
        ss += __shfl_down(ss, off, 64);
    }
    __shared__ float red[8];
    int w = t >> 6, l = t & 63;
    if (l == 0) { red[w] = s; red[4 + w] = ss; }
    __syncthreads();
    float fs  = red[0] + red[1] + red[2] + red[3];
    float fss = red[4] + red[5] + red[6] + red[7];
    float mu  = fs * (1.0f / E_);
    float var = fss * (1.0f / E_) - mu * mu;
    float rstd = rsqrtf(var + 1e-5f);

    float4 gg = ((const float4*)g)[t];
    float4 bb = ((const float4*)b)[t];
    ushort4 o;
    o.x = f2bf((x.x - mu) * rstd * gg.x + bb.x);
    o.y = f2bf((x.y - mu) * rstd * gg.y + bb.y);
    o.z = f2bf((x.z - mu) * rstd * gg.z + bb.z);
    o.w = f2bf((x.w - mu) * rstd * gg.w + bb.w);
    ((ushort4*)(dst + (size_t)r * E_))[t] = o;
}

// ---------------------------------------------------------------------------
// Transpose + cast fp32 [K=1024][N=1024] -> bf16 [N][K]. 32x32 tiles.
// grid (32, 32, 4): z selects Wq/Wk/Wv/Wp.
// ---------------------------------------------------------------------------
__global__ __launch_bounds__(256) void wcast_t(
    const float* __restrict__ wq, const float* __restrict__ wk,
    const float* __restrict__ wv, const float* __restrict__ wp,
    u16* __restrict__ tq, u16* __restrict__ tk,
    u16* __restrict__ tv, u16* __restrict__ tp)
{
    int z = blockIdx.z;
    const float* src = z == 0 ? wq : z == 1 ? wk : z == 2 ? wv : wp;
    u16* dst = z == 0 ? tq : z == 1 ? tk : z == 2 ? tv : tp;
    __shared__ float tile[32][33];
    int n0 = blockIdx.x * 32, k0 = blockIdx.y * 32;
    int tx = threadIdx.x & 31, ty = threadIdx.x >> 5;   // 32 x 8
    for (int i = 0; i < 4; i++)
        tile[ty + i * 8][tx] = src[(size_t)(k0 + ty + i * 8) * E_ + n0 + tx];
    __syncthreads();
    for (int i = 0; i < 4; i++)
        dst[(size_t)(n0 + ty + i * 8) * E_ + k0 + tx] = f2bf(tile[tx][ty + i * 8]);
}

// ---------------------------------------------------------------------------
// GEMM C[4096 x 1024] = X[4096 x 1024] * Wt[1024 x 1024]^T  (bf16 in, f32 acc)
// Tile 128x128, BK=32, 4 waves (2x2), each wave 4x4 16x16 frags.
// mode 0: out bf16 scatter [B,H,T,64]   (q/k heads)
// mode 2: out bf16 scatter [B,H,64,T]   (v transposed)
// mode 3: out f32 row-major + bias      (final projection)
// ---------------------------------------------------------------------------
__global__ __launch_bounds__(256) void gemm_bt(
    const u16* __restrict__ X, const u16* __restrict__ Wt,
    u16* __restrict__ outB, float* __restrict__ outF,
    const float* __restrict__ bias, int mode)
{
    const int K = 1024;
    int n0 = blockIdx.x * 128;
    int m0 = blockIdx.y * 128;
    int t = threadIdx.x, w = t >> 6, l = t & 63;
    int lr = l & 15, lg = l >> 4;
    int wm = w >> 1, wn = w & 1;

    __shared__ __attribute__((aligned(16))) u16 As[128 * 32];
    __shared__ __attribute__((aligned(16))) u16 Bs[128 * 32];

    f32x4 acc[4][4];
    f32x4 zero = {0.f, 0.f, 0.f, 0.f};
    for (int i = 0; i < 4; i++)
        for (int j = 0; j < 4; j++) acc[i][j] = zero;

    const char* Xb = (const char*)X + (size_t)m0 * K * 2;
    const char* Wb = (const char*)Wt + (size_t)n0 * K * 2;

    for (int k0 = 0; k0 < K; k0 += 32) {
        for (int j = 0; j < 2; j++) {
            int cbase = (w * 2 + j) * 1024;          // wave-uniform LDS byte base
            int off = cbase + l * 16;                // this lane's byte in tile
            int row = off >> 6, colb = off & 63;     // 64B per row (32 bf16)
            gll16(Xb + (size_t)row * (K * 2) + k0 * 2 + colb, (char*)As + cbase);
            gll16(Wb + (size_t)row * (K * 2) + k0 * 2 + colb, (char*)Bs + cbase);
        }
        __syncthreads();
        bf16x8 af[4], bfr[4];
        for (int i = 0; i < 4; i++)
            af[i] = *(const bf16x8*)&As[(wm * 64 + i * 16 + lr) * 32 + lg * 8];
        for (int j = 0; j < 4; j++)
            bfr[j] = *(const bf16x8*)&Bs[(wn * 64 + j * 16 + lr) * 32 + lg * 8];
        for (int i = 0; i < 4; i++)
            for (int j = 0; j < 4; j++)
                acc[i][j] = __builtin_amdgcn_mfma_f32_16x16x32_bf16(
                    af[i], bfr[j], acc[i][j], 0, 0, 0);
        __syncthreads();
    }

    for (int i = 0; i < 4; i++)
        for (int j = 0; j < 4; j++)
            for (int r = 0; r < 4; r++) {
                int row = m0 + wm * 64 + i * 16 + lg * 4 + r;
                int col = n0 + wn * 64 + j * 16 + lr;
                float val = acc[i][j][r];
                if (mode == 3) {
                    outF[(size_t)row * E_ + col] = val + bias[col];
                } else {
                    int bb = row >> 10, tt = row & 1023;
                    int hh = col >> 6, dd = col & 63;
                    if (mode == 2)
                        outB[(((size_t)(bb * H_ + hh)) * HS_ + dd) * T_ + tt] = f2bf(val);
                    else
                        outB[(((size_t)(bb * H_ + hh)) * T_ + tt) * HS_ + dd] = f2bf(val);
                }
            }
}

// ---------------------------------------------------------------------------
// Flash attention, causal. grid (16 qtiles, 64 bh). Block = 4 waves; wave w
// owns q rows [qt*64 + w*16, +16). K: [B,H,T,64] bf16. Vt: [B,H,64,T] bf16.
// Out: [B,T,E] bf16 (head-concat layout, input to final projection).
// ---------------------------------------------------------------------------
__global__ __launch_bounds__(256) void attn(
    const u16* __restrict__ Qh, const u16* __restrict__ Kh,
    const u16* __restrict__ Vt, u16* __restrict__ Out)
{
    int qt = blockIdx.x;
    int bh = blockIdx.y;
    int b = bh >> 4, h = bh & 15;
    int t = threadIdx.x, w = t >> 6, l = t & 63;
    int lr = l & 15, lg = l >> 4;

    __shared__ __attribute__((aligned(16))) u16 Ks[64 * 64];
    __shared__ __attribute__((aligned(16))) u16 Vs[64 * 64];
    __shared__ __attribute__((aligned(16))) u16 Ps[4][16 * 64];

    const char* Kb = (const char*)(Kh + (size_t)bh * T_ * HS_);
    const char* Vb = (const char*)(Vt + (size_t)bh * HS_ * T_);
    const u16*  Qb = Qh + (size_t)bh * T_ * HS_;

    int qrow = qt * 64 + w * 16 + lr;
    bf16x8 qf0 = *(const bf16x8*)&Qb[qrow * 64 + lg * 8];
    bf16x8 qf1 = *(const bf16x8*)&Qb[qrow * 64 + 32 + lg * 8];

    f32x4 zero = {0.f, 0.f, 0.f, 0.f};
    f32x4 o[4];
    float m[4], lsum[4];
    for (int i = 0; i < 4; i++) o[i] = zero;
    for (int r = 0; r < 4; r++) { m[r] = -1e30f; lsum[r] = 0.f; }

    int nkv = qt + 1;
    for (int kt = 0; kt < nkv; kt++) {
        int kv0 = kt * 64;
        for (int j = 0; j < 2; j++) {
            int cbase = (w * 2 + j) * 1024;
            gll16(Kb + kv0 * 128 + cbase + l * 16, (char*)Ks + cbase);
            int off = cbase + l * 16;
            int row = off >> 7, colb = off & 127;   // Vt tile rows are 128B
            gll16(Vb + (size_t)row * (T_ * 2) + kv0 * 2 + colb, (char*)Vs + cbase);
        }
        __syncthreads();

        // S = Q K^T  (per wave: 16 q-rows x 64 keys)
        f32x4 s[4];
        for (int kf = 0; kf < 4; kf++) {
            s[kf] = zero;
            bf16x8 bk0 = *(const bf16x8*)&Ks[(kf * 16 + lr) * 64 + lg * 8];
            bf16x8 bk1 = *(const bf16x8*)&Ks[(kf * 16 + lr) * 64 + 32 + lg * 8];
            s[kf] = __builtin_amdgcn_mfma_f32_16x16x32_bf16(qf0, bk0, s[kf], 0, 0, 0);
            s[kf] = __builtin_amdgcn_mfma_f32_16x16x32_bf16(qf1, bk1, s[kf], 0, 0, 0);
        }

        const float sc = 0.03125f;   // E^-0.5
        bool diag = (kt == qt);
        for (int kf = 0; kf < 4; kf++)
            for (int r = 0; r < 4; r++) {
                float sv = s[kf][r] * sc;
                if (diag) {
                    int key = kv0 + kf * 16 + lr;
                    int qr  = qt * 64 + w * 16 + lg * 4 + r;
                    if (key > qr) sv = -1e30f;
                }
                s[kf][r] = sv;
            }

        float al[4];
        for (int r = 0; r < 4; r++) {
            float mt = fmaxf(fmaxf(s[0][r], s[1][r]), fmaxf(s[2][r], s[3][r]));
            for (int off = 1; off < 16; off <<= 1) mt = fmaxf(mt, __shfl_xor(mt, off, 64));
            float mn = fmaxf(m[r], mt);
            al[r] = __expf(m[r] - mn);
            m[r] = mn;
        }
        float rs[4] = {0.f, 0.f, 0.f, 0.f};
        for (int kf = 0; kf < 4; kf++)
            for (int r = 0; r < 4; r++) {
                float p = __expf(s[kf][r] - m[r]);
                s[kf][r] = p;
                rs[r] += p;
            }
        for (int r = 0; r < 4; r++) {
            for (int off = 1; off < 16; off <<= 1) rs[r] += __shfl_xor(rs[r], off, 64);
            lsum[r] = lsum[r] * al[r] + rs[r];
        }
        for (int nf = 0; nf < 4; nf++)
            for (int r = 0; r < 4; r++) o[nf][r] *= al[r];

        // P -> per-wave LDS (re-layout for PV A-fragment)
        for (int kf = 0; kf < 4; kf++)
            for (int r = 0; r < 4; r++)
                Ps[w][(lg * 4 + r) * 64 + kf * 16 + lr] = f2bf(s[kf][r]);

        // O += P V   (A from Ps, B from Vs = V^T)
        for (int ks = 0; ks < 2; ks++) {
            bf16x8 pa = *(const bf16x8*)&Ps[w][lr * 64 + ks * 32 + lg * 8];
            for (int nf = 0; nf < 4; nf++) {
                bf16x8 bv = *(const bf16x8*)&Vs[(nf * 16 + lr) * 64 + ks * 32 + lg * 8];
                o[nf] = __builtin_amdgcn_mfma_f32_16x16x32_bf16(pa, bv, o[nf], 0, 0, 0);
            }
        }
        __syncthreads();
    }

    for (int nf = 0; nf < 4; nf++)
        for (int r = 0; r < 4; r++) {
            int row = qt * 64 + w * 16 + lg * 4 + r;
            int col = h * 64 + nf * 16 + lr;
            Out[((size_t)(b * T_ + row)) * E_ + col] = f2bf(o[nf][r] / lsum[r]);
        }
}

// ---------------------------------------------------------------------------
extern "C" void kernel_launch(void* const* d_in, const int* in_sizes, int n_in,
                              void* d_out, int out_size, void* d_ws, size_t ws_size,
                              hipStream_t stream) {
    const float* v  = (const float*)d_in[0];
    const float* k  = (const float*)d_in[1];
    const float* q  = (const float*)d_in[2];
    const float* g  = (const float*)d_in[3];
    const float* be = (const float*)d_in[4];
    const float* Wq = (const float*)d_in[5];
    const float* Wk = (const float*)d_in[6];
    const float* Wv = (const float*)d_in[7];
    const float* Wp = (const float*)d_in[8];
    const float* bp = (const float*)d_in[9];
    float* out = (float*)d_out;

    char* ws = (char*)d_ws;
    u16* qh  = (u16*)(ws);                // 8MB [B,H,T,64]
    u16* kh  = (u16*)(ws + (8u  << 20));  // 8MB [B,H,T,64]
    u16* vt  = (u16*)(ws + (16u << 20));  // 8MB [B,H,64,T]
    u16* qn  = (u16*)(ws + (24u << 20));  // 8MB [B,T,E]
    u16* kn  = (u16*)(ws + (32u << 20));  // 8MB
    u16* vn  = (u16*)(ws + (40u << 20));  // 8MB
    u16* wtq = (u16*)(ws + (48u << 20));  // 2MB each
    u16* wtk = (u16*)(ws + (50u << 20));
    u16* wtv = (u16*)(ws + (52u << 20));
    u16* wtp = (u16*)(ws + (54u << 20));
    u16* ao  = (u16*)(ws + (24u << 20));  // alias qn (dead after projections)

    hipLaunchKernelGGL(wcast_t, dim3(32, 32, 4), dim3(256), 0, stream,
                       Wq, Wk, Wv, Wp, wtq, wtk, wtv, wtp);
    hipLaunchKernelGGL(ln_all, dim3(3 * BT_), dim3(256), 0, stream,
                       v, k, q, g, be, vn, kn, qn);
    hipLaunchKernelGGL(gemm_bt, dim3(8, 32), dim3(256), 0, stream,
                       qn, wtq, qh, (float*)nullptr, (const float*)nullptr, 0);
    hipLaunchKernelGGL(gemm_bt, dim3(8, 32), dim3(256), 0, stream,
                       kn, wtk, kh, (float*)nullptr, (const float*)nullptr, 0);
    hipLaunchKernelGGL(gemm_bt, dim3(8, 32), dim3(256), 0, stream,
                       vn, wtv, vt, (float*)nullptr, (const float*)nullptr, 2);
    hipLaunchKernelGGL(attn, dim3(16, 64), dim3(256), 0, stream,
                       qh, kh, vt, ao);
    hipLaunchKernelGGL(gemm_bt, dim3(8, 32), dim3(256), 0, stream,
                       ao, wtp, (u16*)nullptr, out, bp, 3);
}

// Round 2
// 240.502 us; speedup vs baseline: 1.2757x; 1.2757x over previous
//
#include <hip/hip_runtime.h>
#include <stdint.h>

#define B_ 4
#define T_ 1024
#define E_ 1024
#define H_ 16
#define HS_ 64
#define BT_ 4096

typedef unsigned short u16;
typedef __attribute__((ext_vector_type(8))) short bf16x8;
typedef __attribute__((ext_vector_type(4))) float f32x4;

__device__ __forceinline__ u16 f2bf(float f) {
    unsigned u = __float_as_uint(f);
    u += 0x7fff + ((u >> 16) & 1);   // round-to-nearest-even
    return (u16)(u >> 16);
}

__device__ __forceinline__ void gll16(const void* g, void* l) {
    __builtin_amdgcn_global_load_lds(
        (const __attribute__((address_space(1))) unsigned int*)g,
        (__attribute__((address_space(3))) unsigned int*)l, 16, 0, 0);
}

// ---------------------------------------------------------------------------
// LayerNorm for all three streams. One block (256 thr) per row of 1024.
// ---------------------------------------------------------------------------
__global__ __launch_bounds__(256) void ln_all(
    const float* __restrict__ v, const float* __restrict__ k,
    const float* __restrict__ q, const float* __restrict__ g,
    const float* __restrict__ b,
    u16* __restrict__ vn, u16* __restrict__ kn, u16* __restrict__ qn)
{
    int row = blockIdx.x;
    int which = row >> 12;
    int r = row & 4095;
    const float* src = which == 0 ? v : which == 1 ? k : q;
    u16* dst = which == 0 ? vn : which == 1 ? kn : qn;

    int t = threadIdx.x;
    float4 x = ((const float4*)(src + (size_t)r * E_))[t];
    float s  = x.x + x.y + x.z + x.w;
    float ss = x.x * x.x + x.y * x.y + x.z * x.z + x.w * x.w;
    for (int off = 32; off; off >>= 1) {
        s  += __shfl_down(s, off, 64);
        ss += __shfl_down(ss, off, 64);
    }
    __shared__ float red[8];
    int w = t >> 6, l = t & 63;
    if (l == 0) { red[w] = s; red[4 + w] = ss; }
    __syncthreads();
    float fs  = red[0] + red[1] + red[2] + red[3];
    float fss = red[4] + red[5] + red[6] + red[7];
    float mu  = fs * (1.0f / E_);
    float var = fss * (1.0f / E_) - mu * mu;
    float rstd = rsqrtf(var + 1e-5f);

    float4 gg = ((const float4*)g)[t];
    float4 bb = ((const float4*)b)[t];
    ushort4 o;
    o.x = f2bf((x.x - mu) * rstd * gg.x + bb.x);
    o.y = f2bf((x.y - mu) * rstd * gg.y + bb.y);
    o.z = f2bf((x.z - mu) * rstd * gg.z + bb.z);
    o.w = f2bf((x.w - mu) * rstd * gg.w + bb.w);
    ((ushort4*)(dst + (size_t)r * E_))[t] = o;
}

// ---------------------------------------------------------------------------
// Transpose + cast fp32 [K][N] -> bf16 [N][K]. 32x32 tiles.
// ---------------------------------------------------------------------------
__global__ __launch_bounds__(256) void wcast_t(
    const float* __restrict__ wq, const float* __restrict__ wk,
    const float* __restrict__ wv, const float* __restrict__ wp,
    u16* __restrict__ tq, u16* __restrict__ tk,
    u16* __restrict__ tv, u16* __restrict__ tp)
{
    int z = blockIdx.z;
    const float* src = z == 0 ? wq : z == 1 ? wk : z == 2 ? wv : wp;
    u16* dst = z == 0 ? tq : z == 1 ? tk : z == 2 ? tv : tp;
    __shared__ float tile[32][33];
    int n0 = blockIdx.x * 32, k0 = blockIdx.y * 32;
    int tx = threadIdx.x & 31, ty = threadIdx.x >> 5;   // 32 x 8
    for (int i = 0; i < 4; i++)
        tile[ty + i * 8][tx] = src[(size_t)(k0 + ty + i * 8) * E_ + n0 + tx];
    __syncthreads();
    for (int i = 0; i < 4; i++)
        dst[(size_t)(n0 + ty + i * 8) * E_ + k0 + tx] = f2bf(tile[tx][ty + i * 8]);
}

// ---------------------------------------------------------------------------
// Shared double-buffered GEMM K-loop: C[128x128] += X[128xK] * Wt[128xK]^T
// As/Bs live in smem[0..32KB): [2 bufs][128 rows][32 bf16].
// ---------------------------------------------------------------------------
__device__ __forceinline__ void gemm_kloop(
    const char* Xb, const char* Wb, char* smem, int w, int l,
    int wm, int wn, int lr, int lg, f32x4 acc[4][4])
{
    const int K = 1024;
    u16* As0 = (u16*)smem;              // 2 x 4096 u16
    u16* Bs0 = (u16*)(smem + 16384);    // 2 x 4096 u16

    int cbase = w * 2048;                // this wave's 2KB stage region (bytes)
    int off0 = cbase + l * 16;
    int row0 = off0 >> 6, colb0 = off0 & 63;
    int off1 = off0 + 1024;
    int row1 = off1 >> 6, colb1 = off1 & 63;

    // prologue: stage k0 = 0 into buffer 0
    gll16(Xb + (size_t)row0 * 2048 + colb0, smem + cbase);
    gll16(Xb + (size_t)row1 * 2048 + colb1, smem + cbase + 1024);
    gll16(Wb + (size_t)row0 * 2048 + colb0, smem + 16384 + cbase);
    gll16(Wb + (size_t)row1 * 2048 + colb1, smem + 16384 + cbase + 1024);
    __syncthreads();

    int b = 0;
    for (int k0 = 0; k0 < K; k0 += 32) {
        if (k0 + 32 < K) {
            int nb = (b ^ 1) * 8192;
            int kb = (k0 + 32) * 2;
            gll16(Xb + (size_t)row0 * 2048 + kb + colb0, smem + nb + cbase);
            gll16(Xb + (size_t)row1 * 2048 + kb + colb1, smem + nb + cbase + 1024);
            gll16(Wb + (size_t)row0 * 2048 + kb + colb0, smem + 16384 + nb + cbase);
            gll16(Wb + (size_t)row1 * 2048 + kb + colb1, smem + 16384 + nb + cbase + 1024);
        }
        const u16* As = As0 + b * 4096;
        const u16* Bs = Bs0 + b * 4096;
        bf16x8 af[4], bfr[4];
        for (int i = 0; i < 4; i++)
            af[i] = *(const bf16x8*)&As[(wm * 64 + i * 16 + lr) * 32 + lg * 8];
        for (int j = 0; j < 4; j++)
            bfr[j] = *(const bf16x8*)&Bs[(wn * 64 + j * 16 + lr) * 32 + lg * 8];
        for (int i = 0; i < 4; i++)
            for (int j = 0; j < 4; j++)
                acc[i][j] = __builtin_amdgcn_mfma_f32_16x16x32_bf16(
                    af[i], bfr[j], acc[i][j], 0, 0, 0);
        __syncthreads();
        b ^= 1;
    }
}

// ---------------------------------------------------------------------------
// Fused QKV projection: grid (8, 32, 3). z picks stream.
// z=0/1 -> bf16 scatter [B,H,T,64]; z=2 -> bf16 [B,H,64,T] via LDS transpose.
// ---------------------------------------------------------------------------
__global__ __launch_bounds__(256) void gemm_qkv(
    const u16* __restrict__ qn, const u16* __restrict__ kn, const u16* __restrict__ vn,
    const u16* __restrict__ wq, const u16* __restrict__ wk, const u16* __restrict__ wv,
    u16* __restrict__ qh, u16* __restrict__ kh, u16* __restrict__ vt)
{
    __shared__ __attribute__((aligned(16))) char smem[36864];
    int z = blockIdx.z;
    const u16* X  = z == 0 ? qn : z == 1 ? kn : vn;
    const u16* Wt = z == 0 ? wq : z == 1 ? wk : wv;

    int n0 = blockIdx.x * 128, m0 = blockIdx.y * 128;
    int t = threadIdx.x, w = t >> 6, l = t & 63;
    int lr = l & 15, lg = l >> 4, wm = w >> 1, wn = w & 1;

    f32x4 acc[4][4];
    f32x4 zero = {0.f, 0.f, 0.f, 0.f};
    for (int i = 0; i < 4; i++)
        for (int j = 0; j < 4; j++) acc[i][j] = zero;

    gemm_kloop((const char*)X + (size_t)m0 * 2048,
               (const char*)Wt + (size_t)n0 * 2048,
               smem, w, l, wm, wn, lr, lg, acc);

    if (z < 2) {
        u16* outB = z == 0 ? qh : kh;
        for (int i = 0; i < 4; i++)
            for (int j = 0; j < 4; j++)
                for (int r = 0; r < 4; r++) {
                    int row = m0 + wm * 64 + i * 16 + lg * 4 + r;
                    int col = n0 + wn * 64 + j * 16 + lr;
                    int bb = row >> 10, tt = row & 1023;
                    int hh = col >> 6, dd = col & 63;
                    outB[(((size_t)(bb * H_ + hh)) * T_ + tt) * HS_ + dd] =
                        f2bf(acc[i][j][r]);
                }
    } else {
        // transpose the wave's 64x64 sub-tile through LDS, store [d][t] coalesced
        u16* Tt = (u16*)smem + w * (64 * 72);   // [64 d][72] u16, 144B rows
        for (int i = 0; i < 4; i++)
            for (int j = 0; j < 4; j++)
                for (int r = 0; r < 4; r++)
                    Tt[(j * 16 + lr) * 72 + i * 16 + lg * 4 + r] = f2bf(acc[i][j][r]);
        __syncthreads();
        int bb = m0 >> 10;
        int tbase = (m0 & 1023) + wm * 64;
        int hh = (n0 + wn * 64) >> 6;
        u16* outV = vt + ((size_t)(bb * H_ + hh)) * HS_ * T_;
        int dl = l >> 3, tc = l & 7;
        for (int u = 0; u < 8; u++) {
            int d = u * 8 + dl;
            bf16x8 vv = *(const bf16x8*)&Tt[d * 72 + tc * 8];
            *(bf16x8*)&outV[(size_t)d * T_ + tbase + tc * 8] = vv;
        }
    }
}

// ---------------------------------------------------------------------------
// Final projection: C = AO * Wp^T + bp, f32 out. grid (8, 32).
// ---------------------------------------------------------------------------
__global__ __launch_bounds__(256) void gemm_fin(
    const u16* __restrict__ X, const u16* __restrict__ Wt,
    float* __restrict__ outF, const float* __restrict__ bias)
{
    __shared__ __attribute__((aligned(16))) char smem[32768];
    int n0 = blockIdx.x * 128, m0 = blockIdx.y * 128;
    int t = threadIdx.x, w = t >> 6, l = t & 63;
    int lr = l & 15, lg = l >> 4, wm = w >> 1, wn = w & 1;

    f32x4 acc[4][4];
    f32x4 zero = {0.f, 0.f, 0.f, 0.f};
    for (int i = 0; i < 4; i++)
        for (int j = 0; j < 4; j++) acc[i][j] = zero;

    gemm_kloop((const char*)X + (size_t)m0 * 2048,
               (const char*)Wt + (size_t)n0 * 2048,
               smem, w, l, wm, wn, lr, lg, acc);

    for (int i = 0; i < 4; i++)
        for (int j = 0; j < 4; j++)
            for (int r = 0; r < 4; r++) {
                int row = m0 + wm * 64 + i * 16 + lg * 4 + r;
                int col = n0 + wn * 64 + j * 16 + lr;
                outF[(size_t)row * E_ + col] = acc[i][j][r] + bias[col];
            }
}

// ---------------------------------------------------------------------------
// Flash attention, causal. grid (16 qtiles, 64 bh), heavy tiles first.
// K: [B,H,T,64] bf16. Vt: [B,H,64,T] bf16. Double-buffered K/V staging with
// XOR-swizzled LDS (source-swizzled for global_load_lds, swizzled reads).
// ---------------------------------------------------------------------------
__global__ __launch_bounds__(256) void attn(
    const u16* __restrict__ Qh, const u16* __restrict__ Kh,
    const u16* __restrict__ Vt, u16* __restrict__ Out)
{
    int qt = 15 - blockIdx.x;          // heavy blocks dispatch first
    int bh = blockIdx.y;
    int b = bh >> 4, h = bh & 15;
    int t = threadIdx.x, w = t >> 6, l = t & 63;
    int lr = l & 15, lg = l >> 4;
    int sw = lr & 7;                   // read-side swizzle key (row&7)

    __shared__ __attribute__((aligned(16))) u16 Ks[2][4096];
    __shared__ __attribute__((aligned(16))) u16 Vs[2][4096];
    __shared__ __attribute__((aligned(16))) u16 Ps[4][1024];

    const char* Kb = (const char*)(Kh + (size_t)bh * T_ * HS_);
    const char* Vb = (const char*)(Vt + (size_t)bh * HS_ * T_);
    const u16*  Qb = Qh + (size_t)bh * T_ * HS_;

    // staging lane constants: LDS[row][c] = src[row][c ^ (row&7)] (16B chunks)
    int ris = l >> 3;                  // row within 8-row segment
    int csw = (l & 7) ^ ris;           // pre-swizzled source chunk

    int qrow = qt * 64 + w * 16 + lr;
    bf16x8 qf0 = *(const bf16x8*)&Qb[qrow * 64 + lg * 8];
    bf16x8 qf1 = *(const bf16x8*)&Qb[qrow * 64 + 32 + lg * 8];

    f32x4 zero = {0.f, 0.f, 0.f, 0.f};
    f32x4 o[4];
    float m[4], lsum[4];
    for (int i = 0; i < 4; i++) o[i] = zero;
    for (int r = 0; r < 4; r++) { m[r] = -1e30f; lsum[r] = 0.f; }

    int nkv = qt + 1;

    auto stageKV = [&](int kt2, int bsel) {
        int kv0 = kt2 * 64;
        for (int j = 0; j < 2; j++) {
            int seg = w * 2 + j;
            int row = seg * 8 + ris;
            gll16(Kb + (size_t)(kv0 + row) * 128 + csw * 16,
                  (char*)Ks[bsel] + seg * 1024);
            gll16(Vb + (size_t)row * 2048 + (size_t)kv0 * 2 + csw * 16,
                  (char*)Vs[bsel] + seg * 1024);
        }
    };

    stageKV(0, 0);
    __syncthreads();
    int bsel = 0;

    for (int kt = 0; kt < nkv; kt++) {
        if (kt + 1 < nkv) stageKV(kt + 1, bsel ^ 1);

        int kv0 = kt * 64;
        const u16* Kl = Ks[bsel];
        const u16* Vl = Vs[bsel];

        // S = Q K^T (swizzled B-frag reads: chunk = c ^ (key&7), key&7 == lr&7)
        f32x4 s[4];
        for (int kf = 0; kf < 4; kf++) {
            int key = kf * 16 + lr;
            s[kf] = zero;
            bf16x8 bk0 = *(const bf16x8*)&Kl[key * 64 + (lg ^ sw) * 8];
            bf16x8 bk1 = *(const bf16x8*)&Kl[key * 64 + ((lg + 4) ^ sw) * 8];
            s[kf] = __builtin_amdgcn_mfma_f32_16x16x32_bf16(qf0, bk0, s[kf], 0, 0, 0);
            s[kf] = __builtin_amdgcn_mfma_f32_16x16x32_bf16(qf1, bk1, s[kf], 0, 0, 0);
        }

        const float sc = 0.03125f;     // E^-0.5
        bool diag = (kt == qt);
        for (int kf = 0; kf < 4; kf++)
            for (int r = 0; r < 4; r++) {
                float sv = s[kf][r] * sc;
                if (diag) {
                    int key = kv0 + kf * 16 + lr;
                    int qr  = qt * 64 + w * 16 + lg * 4 + r;
                    if (key > qr) sv = -1e30f;
                }
                s[kf][r] = sv;
            }

        float al[4];
        for (int r = 0; r < 4; r++) {
            float mt = fmaxf(fmaxf(s[0][r], s[1][r]), fmaxf(s[2][r], s[3][r]));
            for (int off = 1; off < 16; off <<= 1) mt = fmaxf(mt, __shfl_xor(mt, off, 64));
            float mn = fmaxf(m[r], mt);
            al[r] = __expf(m[r] - mn);
            m[r] = mn;
        }
        float rs[4] = {0.f, 0.f, 0.f, 0.f};
        for (int kf = 0; kf < 4; kf++)
            for (int r = 0; r < 4; r++) {
                float p = __expf(s[kf][r] - m[r]);
                s[kf][r] = p;
                rs[r] += p;
            }
        for (int r = 0; r < 4; r++) {
            for (int off = 1; off < 16; off <<= 1) rs[r] += __shfl_xor(rs[r], off, 64);
            lsum[r] = lsum[r] * al[r] + rs[r];
        }
        for (int nf = 0; nf < 4; nf++)
            for (int r = 0; r < 4; r++) o[nf][r] *= al[r];

        // P -> per-wave LDS (swizzled write: chunk ^= row&7)
        for (int kf = 0; kf < 4; kf++)
            for (int r = 0; r < 4; r++) {
                int row = lg * 4 + r;
                int ch  = (kf * 2 + (lr >> 3)) ^ (row & 7);
                Ps[w][row * 64 + ch * 8 + sw] = f2bf(s[kf][r]);
            }

        // O += P V   (A from Ps, B from Vs; both swizzle-read)
        for (int ks = 0; ks < 2; ks++) {
            bf16x8 pa = *(const bf16x8*)&Ps[w][lr * 64 + ((ks * 4 + lg) ^ sw) * 8];
            for (int nf = 0; nf < 4; nf++) {
                int d = nf * 16 + lr;
                bf16x8 bv = *(const bf16x8*)&Vl[d * 64 + ((ks * 4 + lg) ^ sw) * 8];
                o[nf] = __builtin_amdgcn_mfma_f32_16x16x32_bf16(pa, bv, o[nf], 0, 0, 0);
            }
        }
        __syncthreads();
        bsel ^= 1;
    }

    for (int nf = 0; nf < 4; nf++)
        for (int r = 0; r < 4; r++) {
            int row = qt * 64 + w * 16 + lg * 4 + r;
            int col = h * 64 + nf * 16 + lr;
            Out[((size_t)(b * T_ + row)) * E_ + col] = f2bf(o[nf][r] / lsum[r]);
        }
}

// ---------------------------------------------------------------------------
extern "C" void kernel_launch(void* const* d_in, const int* in_sizes, int n_in,
                              void* d_out, int out_size, void* d_ws, size_t ws_size,
                              hipStream_t stream) {
    const float* v  = (const float*)d_in[0];
    const float* k  = (const float*)d_in[1];
    const float* q  = (const float*)d_in[2];
    const float* g  = (const float*)d_in[3];
    const float* be = (const float*)d_in[4];
    const float* Wq = (const float*)d_in[5];
    const float* Wk = (const float*)d_in[6];
    const float* Wv = (const float*)d_in[7];
    const float* Wp = (const float*)d_in[8];
    const float* bp = (const float*)d_in[9];
    float* out = (float*)d_out;

    char* ws = (char*)d_ws;
    u16* qh  = (u16*)(ws);                // 8MB [B,H,T,64]
    u16* kh  = (u16*)(ws + (8u  << 20));  // 8MB [B,H,T,64]
    u16* vt  = (u16*)(ws + (16u << 20));  // 8MB [B,H,64,T]
    u16* qn  = (u16*)(ws + (24u << 20));  // 8MB [B,T,E]
    u16* kn  = (u16*)(ws + (32u << 20));  // 8MB
    u16* vn  = (u16*)(ws + (40u << 20));  // 8MB
    u16* wtq = (u16*)(ws + (48u << 20));  // 2MB each
    u16* wtk = (u16*)(ws + (50u << 20));
    u16* wtv = (u16*)(ws + (52u << 20));
    u16* wtp = (u16*)(ws + (54u << 20));
    u16* ao  = (u16*)(ws + (24u << 20));  // alias qn (dead after projections)

    hipLaunchKernelGGL(wcast_t, dim3(32, 32, 4), dim3(256), 0, stream,
                       Wq, Wk, Wv, Wp, wtq, wtk, wtv, wtp);
    hipLaunchKernelGGL(ln_all, dim3(3 * BT_), dim3(256), 0, stream,
                       v, k, q, g, be, vn, kn, qn);
    hipLaunchKernelGGL(gemm_qkv, dim3(8, 32, 3), dim3(256), 0, stream,
                       qn, kn, vn, wtq, wtk, wtv, qh, kh, vt);
    hipLaunchKernelGGL(attn, dim3(16, 64), dim3(256), 0, stream,
                       qh, kh, vt, ao);
    hipLaunchKernelGGL(gemm_fin, dim3(8, 32), dim3(256), 0, stream,
                       ao, wtp, out, bp);
}